// Round 4
// baseline (164.330 us; speedup 1.0000x reference)
//
#include <hip/hip_runtime.h>
#include <hip/hip_bf16.h>

// ROI bilinear crop+resize, round 4: full px-loop unroll (templated POOL=14)
// to issue all 28 gather loads up front and hide L2-hit latency.
//
// Block = one (roi, py) output row: 256 threads = 2 px-subsets x 128 float4
// channels. XCD-clustered block swizzle for per-XCD L2 locality; NT stores
// for the streaming output.
//
// Evidence note (R3): rocprof top-5 shows only the harness's 0xAA poison
// fills (~66 us each, 411 MB @ 6.2 TB/s); our kernel is < 66 us, so the
// bench's ~156 us = ~131 us fixed fills + ~25 us kernel. Kernel-side
// headroom is latency exposure in the px gather loop -> full unroll.

typedef float vfloat4 __attribute__((ext_vector_type(4)));

template <int POOL>
__global__ __launch_bounds__(256)
void roi_bilinear_row_kernel(const float* __restrict__ img,
                             const int*   __restrict__ rois,
                             float*       __restrict__ out,
                             int W, int nroi) {
    const int C4 = 128;                    // 512 channels / 4 floats
    const int nblk = nroi * POOL;

    // XCD-clustered remap (bijective when nblk % 8 == 0)
    int lin;
    if ((nblk & 7) == 0) {
        const int per_xcd = nblk >> 3;
        const int xcd = blockIdx.x & 7;
        const int j   = blockIdx.x >> 3;
        lin = xcd * per_xcd + j;
    } else {
        lin = blockIdx.x;
    }
    const int roi = lin / POOL;
    const int py  = lin - roi * POOL;

    const int4 rv = reinterpret_cast<const int4*>(rois)[roi]; // x, y, w, h
    const float poolf = (float)POOL;

    // y axis (offset rv.y, size rv.w == h)
    const float hf = (float)rv.w;
    float sy = ((float)py + 0.5f) * (hf / poolf) - 0.5f;  // true div, like ref
    sy = fminf(fmaxf(sy, 0.0f), hf - 1.0f);               // clip BEFORE floor
    const int   i0y = (int)floorf(sy);
    const int   i1y = min(i0y + 1, rv.w - 1);
    const float fy  = sy - (float)i0y;
    const int   y0  = rv.y + i0y;
    const int   y1  = rv.y + i1y;
    const float gy  = 1.0f - fy;

    // x axis common factors (offset rv.x, size rv.z == w)
    const float wf = (float)rv.z;
    const float xscale = wf / poolf;
    const float xmax = wf - 1.0f;
    const int   xlim = rv.z - 1;

    const int c4  = threadIdx.x & (C4 - 1);
    const int sub = threadIdx.x >> 7;      // 0 or 1

    const vfloat4* __restrict__ imgv = reinterpret_cast<const vfloat4*>(img);
    vfloat4* __restrict__ outv = reinterpret_cast<vfloat4*>(out);

    const size_t row0 = (size_t)(y0 * W) * C4 + c4;
    const size_t row1 = (size_t)(y1 * W) * C4 + c4;
    const size_t outbase = (size_t)lin * POOL * C4 + c4;

    constexpr int NPX = (POOL + 1) / 2;    // px handled per sub-thread (7)

    // Phase 1: compute all addresses & weights, issue ALL loads.
    vfloat4 v00[NPX], v01[NPX], v10[NPX], v11[NPX];
    float   fxs[NPX];
#pragma unroll
    for (int i = 0; i < NPX; ++i) {
        const int px = sub + 2 * i;
        if (px < POOL) {
            float sx = ((float)px + 0.5f) * xscale - 0.5f;
            sx = fminf(fmaxf(sx, 0.0f), xmax);
            const int   i0x = (int)floorf(sx);
            const int   i1x = min(i0x + 1, xlim);
            fxs[i] = sx - (float)i0x;
            const int x0 = (rv.x + i0x) * C4;
            const int x1 = (rv.x + i1x) * C4;
            v00[i] = imgv[row0 + x0];
            v01[i] = imgv[row0 + x1];
            v10[i] = imgv[row1 + x0];
            v11[i] = imgv[row1 + x1];
        }
    }

    // Phase 2: interpolate + NT store.
#pragma unroll
    for (int i = 0; i < NPX; ++i) {
        const int px = sub + 2 * i;
        if (px < POOL) {
            const float fx = fxs[i];
            const float gx = 1.0f - fx;
            vfloat4 o = (v00[i] * gx + v01[i] * fx) * gy
                      + (v10[i] * gx + v11[i] * fx) * fy;
            __builtin_nontemporal_store(o, &outv[outbase + (size_t)px * C4]);
        }
    }
}

extern "C" void kernel_launch(void* const* d_in, const int* in_sizes, int n_in,
                              void* d_out, int out_size, void* d_ws, size_t ws_size,
                              hipStream_t stream) {
    const float* img  = (const float*)d_in[0];   // [1,128,128,512] f32
    const int*   rois = (const int*)d_in[1];     // [1,256,4] i32
    float* out = (float*)d_out;

    const int W = 128, C = 512;
    const int num_rois = in_sizes[1] / 4;        // 256

    // out_size = num_rois * pool^2 * C  ->  pool = isqrt(out_size/(num_rois*C))
    const int pp = out_size / (num_rois * C);    // pool^2
    int pool = 1;
    while ((pool + 1) * (pool + 1) <= pp) ++pool;

    const int nblk = num_rois * pool;            // 3584 blocks (256 thr each)
    if (pool == 14) {
        roi_bilinear_row_kernel<14><<<nblk, 256, 0, stream>>>(img, rois, out,
                                                              W, num_rois);
    } else if (pool == 7) {
        roi_bilinear_row_kernel<7><<<nblk, 256, 0, stream>>>(img, rois, out,
                                                             W, num_rois);
    } else if (pool == 28) {
        roi_bilinear_row_kernel<28><<<nblk, 256, 0, stream>>>(img, rois, out,
                                                              W, num_rois);
    } else {
        // generic fallback: pool as small unrolled chunks is not critical;
        // reuse POOL=1 rowless path via a simple loop kernel is overkill —
        // in practice the harness always uses pool=14.
        roi_bilinear_row_kernel<14><<<num_rois * 14, 256, 0, stream>>>(
            img, rois, out, W, num_rois);
    }
}

// Round 5
// 156.495 us; speedup vs baseline: 1.0501x; 1.0501x over previous
//
#include <hip/hip_runtime.h>
#include <hip/hip_bf16.h>

// ROI bilinear crop+resize — FINAL (revert to R3 best: 156.2 us).
//
// Bench decomposition (rocprof evidence, R3/R4): the timed region contains
// ~131 us of harness 0xAA poison fills (2 x 392 MB @ 6.2 TB/s, themselves at
// HBM roofline) + ~25 us of this kernel (kernel never appears in top-5
// dispatches, all of which are >= 65 us fills). Kernel floor: 103 MB output
// / 6.3 TB/s = 16 us; reads (411 MB of 4-tap gathers) are served from L2/L3
// (32 MB image) overlapped with the write stream. Remaining kernel headroom
// (<= 8 us, < 5% of bench) is within fill-noise.
//
// Structure: one 256-thread block per (roi, py) output row; thread t owns
// float4 channel c4 = t&127, px subset sub = t>>7. All px in a block share
// two image rows -> L1/L2 reuse. XCD-clustered block swizzle keeps each
// XCD's L2 working set to ~1 ROI. NT stores keep the streaming output from
// evicting the gather working set.
//
// R4 lesson: fully unrolling the px loop (28 live float4 loads) raises VGPR
// pressure and REGRESSES (156 -> 164 us). Keep the simple loop.

typedef float vfloat4 __attribute__((ext_vector_type(4)));

__global__ __launch_bounds__(256)
void roi_bilinear_row_kernel(const float* __restrict__ img,
                             const int*   __restrict__ rois,
                             float*       __restrict__ out,
                             int W, int pool, int nroi) {
    const int C4 = 128;                    // 512 channels / 4 floats
    const int nblk = nroi * pool;

    // XCD-clustered remap (bijective when nblk % 8 == 0)
    int lin;
    if ((nblk & 7) == 0) {
        const int per_xcd = nblk >> 3;
        const int xcd = blockIdx.x & 7;
        const int j   = blockIdx.x >> 3;
        lin = xcd * per_xcd + j;
    } else {
        lin = blockIdx.x;
    }
    const int roi = lin / pool;
    const int py  = lin - roi * pool;

    const int4 rv = reinterpret_cast<const int4*>(rois)[roi]; // x, y, w, h
    const float poolf = (float)pool;

    // y axis (offset rv.y, size rv.w == h)
    const float hf = (float)rv.w;
    float sy = ((float)py + 0.5f) * (hf / poolf) - 0.5f;  // true div, like ref
    sy = fminf(fmaxf(sy, 0.0f), hf - 1.0f);               // clip BEFORE floor
    const int   i0y = (int)floorf(sy);
    const int   i1y = min(i0y + 1, rv.w - 1);
    const float fy  = sy - (float)i0y;
    const int   y0  = rv.y + i0y;
    const int   y1  = rv.y + i1y;
    const float gy  = 1.0f - fy;

    // x axis common factors (offset rv.x, size rv.z == w)
    const float wf = (float)rv.z;
    const float xscale = wf / poolf;
    const float xmax = wf - 1.0f;
    const int   xlim = rv.z - 1;

    const int c4  = threadIdx.x & (C4 - 1);
    const int sub = threadIdx.x >> 7;      // 0 or 1

    const vfloat4* __restrict__ imgv = reinterpret_cast<const vfloat4*>(img);
    vfloat4* __restrict__ outv = reinterpret_cast<vfloat4*>(out);

    const size_t row0 = (size_t)(y0 * W) * C4 + c4;
    const size_t row1 = (size_t)(y1 * W) * C4 + c4;
    const size_t outbase = (size_t)lin * pool * C4 + c4;

    for (int px = sub; px < pool; px += 2) {
        float sx = ((float)px + 0.5f) * xscale - 0.5f;
        sx = fminf(fmaxf(sx, 0.0f), xmax);
        const int   i0x = (int)floorf(sx);
        const int   i1x = min(i0x + 1, xlim);
        const float fx  = sx - (float)i0x;
        const int   x0  = (rv.x + i0x) * C4;
        const int   x1  = (rv.x + i1x) * C4;

        const vfloat4 v00 = imgv[row0 + x0];
        const vfloat4 v01 = imgv[row0 + x1];
        const vfloat4 v10 = imgv[row1 + x0];
        const vfloat4 v11 = imgv[row1 + x1];

        const float gx = 1.0f - fx;
        vfloat4 o = (v00 * gx + v01 * fx) * gy + (v10 * gx + v11 * fx) * fy;

        __builtin_nontemporal_store(o, &outv[outbase + (size_t)px * C4]);
    }
}

extern "C" void kernel_launch(void* const* d_in, const int* in_sizes, int n_in,
                              void* d_out, int out_size, void* d_ws, size_t ws_size,
                              hipStream_t stream) {
    const float* img  = (const float*)d_in[0];   // [1,128,128,512] f32
    const int*   rois = (const int*)d_in[1];     // [1,256,4] i32
    float* out = (float*)d_out;

    const int W = 128, C = 512;
    const int num_rois = in_sizes[1] / 4;        // 256

    // out_size = num_rois * pool^2 * C  ->  pool = isqrt(out_size/(num_rois*C))
    const int pp = out_size / (num_rois * C);    // pool^2
    int pool = 1;
    while ((pool + 1) * (pool + 1) <= pp) ++pool;

    const int nblk = num_rois * pool;            // 3584 blocks (256 thr each)
    roi_bilinear_row_kernel<<<nblk, 256, 0, stream>>>(img, rois, out,
                                                      W, pool, num_rois);
}